// Round 2
// baseline (25299.153 us; speedup 1.0000x reference)
//
#include <hip/hip_runtime.h>
#include <hip/hip_fp16.h>

// Decoder: 2-layer LSTM (H=256), T=512, B=256, scalar output feedback.
// Round 5: v_dot2_f32_f16 inner product. Hidden state h0/h1 stored in LDS as
// fp16 (cell state c stays fp32 in registers; gates, nonlinearities and the
// pred/loss path stay fp32). Each 8-wide weight window is now 4 fdot2
// instructions instead of 8 cvt + 8 fma -> ~3x less VALU issue, h LDS reads
// halve. The 96KB LDS weight cache (also forcing 1 block/CU) is kept.

namespace {

constexpr int kB = 256, kT = 512, kH = 256;
constexpr int kWin = 32;                       // 256 k-values / 8 per window
constexpr int kTiles = kWin * 1024;            // H8 tiles per matrix
constexpr size_t kWsNeeded = 3 * (size_t)kTiles * 16;  // 1.5 MB
constexpr int kLdsWin = 6;                     // whh0 windows cached in LDS (96 KB)

typedef _Float16 h2_t __attribute__((ext_vector_type(2)));
struct alignas(16) H8 { h2_t h[4]; };          // 8 fp16 values

__device__ __forceinline__ float fsig(float v) { return 1.0f / (1.0f + __expf(-v)); }

__device__ __forceinline__ float dot8(H8 w, H8 x, float a) {
#if __has_builtin(__builtin_amdgcn_fdot2)
  a = __builtin_amdgcn_fdot2(w.h[0], x.h[0], a, false);
  a = __builtin_amdgcn_fdot2(w.h[1], x.h[1], a, false);
  a = __builtin_amdgcn_fdot2(w.h[2], x.h[2], a, false);
  a = __builtin_amdgcn_fdot2(w.h[3], x.h[3], a, false);
#else
#pragma unroll
  for (int i = 0; i < 4; ++i) {
    a = fmaf((float)w.h[i][0], (float)x.h[i][0], a);
    a = fmaf((float)w.h[i][1], (float)x.h[i][1], a);
  }
#endif
  return a;
}

// dst[win*1024 + j] holds w[j][8win..8win+7]; lane-consecutive j => coalesced.
__global__ __launch_bounds__(256) void pack_w(const float* __restrict__ s0,
                                              const float* __restrict__ s1,
                                              const float* __restrict__ s2,
                                              H8* __restrict__ dst) {
  int idx = blockIdx.x * 256 + threadIdx.x;       // 0 .. 3*32768-1
  int mat = idx >> 15;                            // 0..2
  int loc = idx & 32767;                          // win*1024 + j
  int j = loc & 1023, win = loc >> 10;
  const float* src = (mat == 0 ? s0 : (mat == 1 ? s1 : s2)) + j * 256 + win * 8;
  H8 o;
#pragma unroll
  for (int i = 0; i < 4; ++i) {
    h2_t v;
    v[0] = (_Float16)src[2 * i];
    v[1] = (_Float16)src[2 * i + 1];
    o.h[i] = v;
  }
  dst[idx] = o;
}

__global__ __launch_bounds__(1024) void decoder_b1(
    const float* __restrict__ seq, const float* __restrict__ z,
    const float* __restrict__ wih0, const float* __restrict__ bih0,
    const float* __restrict__ bhh0, const float* __restrict__ bih1,
    const float* __restrict__ bhh1, const float* __restrict__ wout,
    const float* __restrict__ bout, const H8* __restrict__ w0,
    const H8* __restrict__ w1i, const H8* __restrict__ w1h,
    float* __restrict__ loss_out) {
  extern __shared__ H8 lw[];                      // kLdsWin windows of whh0
  __shared__ alignas(16) _Float16 h0h[kH];        // hidden, layer 0 (fp16)
  __shared__ alignas(16) _Float16 h1h[kH];        // hidden, layer 1 (fp16)
  __shared__ float g4[1024];
  __shared__ float spred[kH];

  const int tid = threadIdx.x;                    // gate row j
  const int b = blockIdx.x;                       // batch element

  // Stage whh0 windows 0..kLdsWin-1 into LDS (coalesced 16B copies).
  {
    const uint4* src = (const uint4*)w0;
    uint4* dst = (uint4*)lw;
#pragma unroll
    for (int i = 0; i < kLdsWin; ++i) dst[i * 1024 + tid] = src[i * 1024 + tid];
  }

  float c0 = 0.f, c1 = 0.f, woutr = 0.f;
  if (tid < kH) {
    float zv = z[(size_t)b * kH + tid];
    h0h[tid] = (_Float16)zv;
    h1h[tid] = (_Float16)zv;
    c0 = zv;
    c1 = zv;
    woutr = wout[tid];
  }
  const float wih0_j = wih0[tid];
  const float bias0 = bih0[tid] + bhh0[tid];
  const float bias1 = bih1[tid] + bhh1[tid];
  const float bo = bout[0];
  const bool isG = (tid >= 512) && (tid < 768);   // wave-uniform (waves 8..11)
  float xsv = 0.f, lacc = 0.f;

  const H8* wp0 = w0 + tid;
  const H8* wpA = w1i + tid;
  const H8* wpB = w1h + tid;
  const H8* lwp = lw + tid;
  const H8* h0w = (const H8*)h0h;                 // 32 windows of 8 halves
  const H8* h1w = (const H8*)h1h;
  __syncthreads();

  for (int t = 0; t < kT; ++t) {
    // ---- layer 0 gates: Whh0 @ h0 + x*wih0 + bias ----
    float a0 = fmaf(xsv, wih0_j, bias0);
#pragma unroll
    for (int win = 0; win < kLdsWin; ++win)       // LDS-cached windows
      a0 = dot8(lwp[win << 10], h0w[win], a0);
#pragma unroll
    for (int win = kLdsWin; win < kWin; ++win)    // L2-streamed windows
      a0 = dot8(wp0[(size_t)win << 10], h0w[win], a0);
    // per-thread nonlinearity: rows 512..767 are gate g (tanh), rest sigmoid
    if (isG) g4[tid] = tanhf(a0); else g4[tid] = fsig(a0);
    __syncthreads();
    if (tid < kH) {
      float gi = g4[tid];
      float gf = g4[tid + 256];
      float gg = g4[tid + 512];
      float go = g4[tid + 768];
      c0 = fmaf(gf, c0, gi * gg);
      h0h[tid] = (_Float16)(go * tanhf(c0));
    }
    __syncthreads();

    // ---- layer 1 gates: Wih1 @ h0new + Whh1 @ h1old + bias ----
    float a1 = bias1;
#pragma unroll
    for (int win = 0; win < kWin; ++win) {
      a1 = dot8(wpA[(size_t)win << 10], h0w[win], a1);
      a1 = dot8(wpB[(size_t)win << 10], h1w[win], a1);
    }
    if (isG) g4[tid] = tanhf(a1); else g4[tid] = fsig(a1);
    __syncthreads();
    if (tid < kH) {
      float gi = g4[tid];
      float gf = g4[tid + 256];
      float gg = g4[tid + 512];
      float go = g4[tid + 768];
      c1 = fmaf(gf, c1, gi * gg);
      float hn = go * tanhf(c1);                  // fp32, pre-rounding
      h1h[tid] = (_Float16)hn;
      spred[tid] = hn * woutr;                    // pred path stays fp32
    }
    __syncthreads();

    // ---- redundant per-wave reduce: pred stays in-register in every wave ----
    {
      int ln = tid & 63;
      float v = spred[ln] + spred[ln + 64] + spred[ln + 128] + spred[ln + 192];
#pragma unroll
      for (int off = 32; off > 0; off >>= 1) v += __shfl_down(v, off);
      float pred = __shfl(v, 0) + bo;             // broadcast within wave
      xsv = pred;                                 // feedback for next step
      if (tid == 0) {
        float d = seq[(size_t)b * kT + t] - pred;
        lacc = fmaf(d, d, lacc);
      }
    }
    // no barrier needed: next writer of spred passes 3 barriers first
  }

  if (tid == 0) atomicAdd(loss_out, lacc * (1.0f / ((float)kB * (float)kT)));
}

// ---------------- fallback (reads d_in directly, fp32) ---------------------
__global__ __launch_bounds__(1024) void decoder_fallback(
    const float* __restrict__ seq, const float* __restrict__ z,
    const float* __restrict__ wih0, const float* __restrict__ bih0,
    const float* __restrict__ bhh0, const float* __restrict__ whh0,
    const float* __restrict__ wih1, const float* __restrict__ whh1,
    const float* __restrict__ bih1, const float* __restrict__ bhh1,
    const float* __restrict__ wout, const float* __restrict__ bout,
    float* __restrict__ loss_out) {
  __shared__ float h0s[kH], h1s[kH], g4[1024];
  __shared__ float xs_s;
  const int tid = threadIdx.x;
  const int b = blockIdx.x;
  float c0r = 0.f, c1r = 0.f;
  if (tid < kH) {
    float zv = z[b * kH + tid];
    h0s[tid] = zv; h1s[tid] = zv; c0r = zv; c1r = zv;
  }
  if (tid == 0) xs_s = 0.f;
  const float wih0_j = wih0[tid];
  const float bias0_j = bih0[tid] + bhh0[tid];
  const float bias1_j = bih1[tid] + bhh1[tid];
  const float wout_r = (tid < kH) ? wout[tid] : 0.f;
  const float bo = bout[0];
  float lacc = 0.f;
  __syncthreads();
  for (int t = 0; t < kT; ++t) {
    float a0 = fmaf(xs_s, wih0_j, bias0_j);
    for (int k = 0; k < kH; ++k) a0 = fmaf(whh0[tid * kH + k], h0s[k], a0);
    g4[tid] = a0;
    __syncthreads();
    if (tid < kH) {
      float ig = fsig(g4[tid]), fg = fsig(g4[tid + 256]);
      float gg = tanhf(g4[tid + 512]), og = fsig(g4[tid + 768]);
      c0r = fmaf(fg, c0r, ig * gg);
      h0s[tid] = og * tanhf(c0r);
    }
    __syncthreads();
    float a1 = bias1_j;
    for (int k = 0; k < kH; ++k) a1 = fmaf(wih1[tid * kH + k], h0s[k], a1);
    for (int k = 0; k < kH; ++k) a1 = fmaf(whh1[tid * kH + k], h1s[k], a1);
    g4[tid] = a1;
    __syncthreads();
    if (tid < kH) {
      float ig = fsig(g4[tid]), fg = fsig(g4[tid + 256]);
      float gg = tanhf(g4[tid + 512]), og = fsig(g4[tid + 768]);
      c1r = fmaf(fg, c1r, ig * gg);
      float h1 = og * tanhf(c1r);
      h1s[tid] = h1;
      g4[tid] = h1 * wout_r;
    }
    __syncthreads();
    if (tid < 64) {
      float v = g4[tid] + g4[tid + 64] + g4[tid + 128] + g4[tid + 192];
#pragma unroll
      for (int off = 32; off > 0; off >>= 1) v += __shfl_down(v, off);
      if (tid == 0) {
        float pred = v + bo;
        float d = seq[b * kT + t] - pred;
        lacc = fmaf(d, d, lacc);
        xs_s = pred;
      }
    }
    __syncthreads();
  }
  if (tid == 0) atomicAdd(loss_out, lacc * (1.0f / (float)(kB * kT)));
}

}  // namespace

extern "C" void kernel_launch(void* const* d_in, const int* in_sizes, int n_in,
                              void* d_out, int out_size, void* d_ws, size_t ws_size,
                              hipStream_t stream) {
  const float* seq = (const float*)d_in[0];
  const float* z = (const float*)d_in[1];
  const float* wih0 = (const float*)d_in[3];
  const float* whh0 = (const float*)d_in[4];
  const float* bih0 = (const float*)d_in[5];
  const float* bhh0 = (const float*)d_in[6];
  const float* wih1 = (const float*)d_in[7];
  const float* whh1 = (const float*)d_in[8];
  const float* bih1 = (const float*)d_in[9];
  const float* bhh1 = (const float*)d_in[10];
  const float* wout = (const float*)d_in[11];
  const float* bout = (const float*)d_in[12];
  float* out = (float*)d_out;

  hipMemsetAsync(out, 0, sizeof(float), stream);

  if (ws_size >= kWsNeeded) {
    H8* wpk = (H8*)d_ws;  // [3][32768] tiles: whh0, wih1, whh1
    pack_w<<<384, 256, 0, stream>>>(whh0, wih1, whh1, wpk);
    // 96KB dynamic LDS weight cache also forces 1 block/CU -> 256 blocks
    // land on 256 distinct CUs (full machine).
    decoder_b1<<<kB, 1024, kLdsWin * 1024 * (int)sizeof(H8), stream>>>(
        seq, z, wih0, bih0, bhh0, bih1, bhh1, wout, bout, wpk,
        wpk + kTiles, wpk + 2 * kTiles, out);
  } else {
    decoder_fallback<<<kB, 1024, 0, stream>>>(seq, z, wih0, bih0, bhh0, whh0,
                                              wih1, whh1, bih1, bhh1, wout, bout,
                                              out);
  }
}

// Round 3
// 6266.809 us; speedup vs baseline: 4.0370x; 4.0370x over previous
//
#include <hip/hip_runtime.h>
#include <hip/hip_fp16.h>

// Decoder: 2-layer LSTM (H=256), T=512, B=256, scalar output feedback.
// Round 6: fdot2 re-applied in the spill-proof round-4 skeleton.
//  - Round 5 post-mortem: H8{ext_vector[4]} by-value + full unroll let LICM
//    hoist ~90 loop-invariant weight loads; regalloc spilled ~1KB/thread to
//    scratch (WRITE_SIZE 274MB, FETCH 68GB of HBM scratch reloads, 25ms).
//  - Fix: weights loaded as plain uint4 (round-1-proven form), bit_cast to
//    half2 per fdot2 operand, round-1 partial unrolls, and an asm-"memory"
//    LICM fence at the top of the t-loop so nothing invariant gets hoisted.
//  - LDS weight cache grown 6 -> 8 windows (128 KB, still forces 1 block/CU).

namespace {

constexpr int kB = 256, kT = 512, kH = 256;
constexpr int kWin = 32;                       // 256 k-values / 8 per window
constexpr int kTiles = kWin * 1024;            // uint4 tiles per matrix
constexpr size_t kWsNeeded = 3 * (size_t)kTiles * 16;  // 1.5 MB
constexpr int kLdsWin = 8;                     // whh0 windows cached in LDS (128 KB)

typedef _Float16 h2_t __attribute__((ext_vector_type(2)));
struct alignas(16) H8 { __half2 h[4]; };       // pack-side view of 8 fp16

__device__ __forceinline__ float fsig(float v) { return 1.0f / (1.0f + __expf(-v)); }

// 8-wide fp16 dot-accumulate from two raw uint4 registers.
__device__ __forceinline__ float dot8(uint4 w, uint4 x, float a) {
#if __has_builtin(__builtin_amdgcn_fdot2)
  a = __builtin_amdgcn_fdot2(__builtin_bit_cast(h2_t, w.x),
                             __builtin_bit_cast(h2_t, x.x), a, false);
  a = __builtin_amdgcn_fdot2(__builtin_bit_cast(h2_t, w.y),
                             __builtin_bit_cast(h2_t, x.y), a, false);
  a = __builtin_amdgcn_fdot2(__builtin_bit_cast(h2_t, w.z),
                             __builtin_bit_cast(h2_t, x.z), a, false);
  a = __builtin_amdgcn_fdot2(__builtin_bit_cast(h2_t, w.w),
                             __builtin_bit_cast(h2_t, x.w), a, false);
#else
  {
    float2 f0 = __half22float2(__builtin_bit_cast(__half2, w.x));
    float2 x0 = __half22float2(__builtin_bit_cast(__half2, x.x));
    float2 f1 = __half22float2(__builtin_bit_cast(__half2, w.y));
    float2 x1 = __half22float2(__builtin_bit_cast(__half2, x.y));
    float2 f2 = __half22float2(__builtin_bit_cast(__half2, w.z));
    float2 x2 = __half22float2(__builtin_bit_cast(__half2, x.z));
    float2 f3 = __half22float2(__builtin_bit_cast(__half2, w.w));
    float2 x3 = __half22float2(__builtin_bit_cast(__half2, x.w));
    a = fmaf(f0.x, x0.x, a); a = fmaf(f0.y, x0.y, a);
    a = fmaf(f1.x, x1.x, a); a = fmaf(f1.y, x1.y, a);
    a = fmaf(f2.x, x2.x, a); a = fmaf(f2.y, x2.y, a);
    a = fmaf(f3.x, x3.x, a); a = fmaf(f3.y, x3.y, a);
  }
#endif
  return a;
}

// dst[win*1024 + j] holds w[j][8win..8win+7]; lane-consecutive j => coalesced.
__global__ __launch_bounds__(256) void pack_w(const float* __restrict__ s0,
                                              const float* __restrict__ s1,
                                              const float* __restrict__ s2,
                                              H8* __restrict__ dst) {
  int idx = blockIdx.x * 256 + threadIdx.x;       // 0 .. 3*32768-1
  int mat = idx >> 15;                            // 0..2
  int loc = idx & 32767;                          // win*1024 + j
  int j = loc & 1023, win = loc >> 10;
  const float* src = (mat == 0 ? s0 : (mat == 1 ? s1 : s2)) + j * 256 + win * 8;
  H8 o;
#pragma unroll
  for (int i = 0; i < 4; ++i) o.h[i] = __floats2half2_rn(src[2 * i], src[2 * i + 1]);
  dst[idx] = o;
}

__global__ __launch_bounds__(1024) void decoder_b1(
    const float* __restrict__ seq, const float* __restrict__ z,
    const float* __restrict__ wih0, const float* __restrict__ bih0,
    const float* __restrict__ bhh0, const float* __restrict__ bih1,
    const float* __restrict__ bhh1, const float* __restrict__ wout,
    const float* __restrict__ bout, const uint4* __restrict__ w0,
    const uint4* __restrict__ w1i, const uint4* __restrict__ w1h,
    float* __restrict__ loss_out) {
  extern __shared__ uint4 lw[];                   // kLdsWin windows of whh0
  __shared__ alignas(16) _Float16 h0h[kH];        // hidden, layer 0 (fp16)
  __shared__ alignas(16) _Float16 h1h[kH];        // hidden, layer 1 (fp16)
  __shared__ float g4[1024];
  __shared__ float spred[kH];

  const int tid = threadIdx.x;                    // gate row j
  const int b = blockIdx.x;                       // batch element

  // Stage whh0 windows 0..kLdsWin-1 into LDS (coalesced 16B copies).
#pragma unroll
  for (int i = 0; i < kLdsWin; ++i) lw[i * 1024 + tid] = w0[i * 1024 + tid];

  float c0 = 0.f, c1 = 0.f, woutr = 0.f;
  if (tid < kH) {
    float zv = z[(size_t)b * kH + tid];
    h0h[tid] = (_Float16)zv;
    h1h[tid] = (_Float16)zv;
    c0 = zv;
    c1 = zv;
    woutr = wout[tid];
  }
  const float wih0_j = wih0[tid];
  const float bias0 = bih0[tid] + bhh0[tid];
  const float bias1 = bih1[tid] + bhh1[tid];
  const float bo = bout[0];
  const bool isG = (tid >= 512) && (tid < 768);   // wave-uniform (waves 8..11)
  float xsv = 0.f, lacc = 0.f;

  const uint4* wp0 = w0 + tid;
  const uint4* wpA = w1i + tid;
  const uint4* wpB = w1h + tid;
  const uint4* lwp = lw + tid;
  const uint4* h0u = (const uint4*)h0h;           // 32 windows of 8 halves
  const uint4* h1u = (const uint4*)h1h;
  __syncthreads();

  for (int t = 0; t < kT; ++t) {
    // LICM fence: no loop-invariant load may be hoisted out of the t-loop
    // (round-5 post-mortem: hoist->spill->268MB scratch->HBM-bound).
    asm volatile("" ::: "memory");

    // ---- layer 0 gates: Whh0 @ h0 + x*wih0 + bias ----
    float a0 = fmaf(xsv, wih0_j, bias0);
#pragma unroll
    for (int win = 0; win < kLdsWin; ++win)       // LDS-cached windows
      a0 = dot8(lwp[win << 10], h0u[win], a0);
#pragma unroll 4
    for (int win = kLdsWin; win < kWin; ++win)    // L2-streamed windows
      a0 = dot8(wp0[(size_t)win << 10], h0u[win], a0);
    // per-thread nonlinearity: rows 512..767 are gate g (tanh), rest sigmoid
    if (isG) g4[tid] = tanhf(a0); else g4[tid] = fsig(a0);
    __syncthreads();
    if (tid < kH) {
      float gi = g4[tid];
      float gf = g4[tid + 256];
      float gg = g4[tid + 512];
      float go = g4[tid + 768];
      c0 = fmaf(gf, c0, gi * gg);
      h0h[tid] = (_Float16)(go * tanhf(c0));
    }
    __syncthreads();

    // ---- layer 1 gates: Wih1 @ h0new + Whh1 @ h1old + bias ----
    float a1 = bias1;
#pragma unroll 2
    for (int win = 0; win < kWin; ++win) {
      a1 = dot8(wpA[(size_t)win << 10], h0u[win], a1);
      a1 = dot8(wpB[(size_t)win << 10], h1u[win], a1);
    }
    if (isG) g4[tid] = tanhf(a1); else g4[tid] = fsig(a1);
    __syncthreads();
    if (tid < kH) {
      float gi = g4[tid];
      float gf = g4[tid + 256];
      float gg = g4[tid + 512];
      float go = g4[tid + 768];
      c1 = fmaf(gf, c1, gi * gg);
      float hn = go * tanhf(c1);                  // fp32, pre-rounding
      h1h[tid] = (_Float16)hn;
      spred[tid] = hn * woutr;                    // pred path stays fp32
    }
    __syncthreads();

    // ---- redundant per-wave reduce: pred stays in-register in every wave ----
    {
      int ln = tid & 63;
      float v = spred[ln] + spred[ln + 64] + spred[ln + 128] + spred[ln + 192];
#pragma unroll
      for (int off = 32; off > 0; off >>= 1) v += __shfl_down(v, off);
      float pred = __shfl(v, 0) + bo;             // broadcast within wave
      xsv = pred;                                 // feedback for next step
      if (tid == 0) {
        float d = seq[(size_t)b * kT + t] - pred;
        lacc = fmaf(d, d, lacc);
      }
    }
    // no barrier needed: next writer of spred passes 3 barriers first
  }

  if (tid == 0) atomicAdd(loss_out, lacc * (1.0f / ((float)kB * (float)kT)));
}

// ---------------- fallback (reads d_in directly, fp32) ---------------------
__global__ __launch_bounds__(1024) void decoder_fallback(
    const float* __restrict__ seq, const float* __restrict__ z,
    const float* __restrict__ wih0, const float* __restrict__ bih0,
    const float* __restrict__ bhh0, const float* __restrict__ whh0,
    const float* __restrict__ wih1, const float* __restrict__ whh1,
    const float* __restrict__ bih1, const float* __restrict__ bhh1,
    const float* __restrict__ wout, const float* __restrict__ bout,
    float* __restrict__ loss_out) {
  __shared__ float h0s[kH], h1s[kH], g4[1024];
  __shared__ float xs_s;
  const int tid = threadIdx.x;
  const int b = blockIdx.x;
  float c0r = 0.f, c1r = 0.f;
  if (tid < kH) {
    float zv = z[b * kH + tid];
    h0s[tid] = zv; h1s[tid] = zv; c0r = zv; c1r = zv;
  }
  if (tid == 0) xs_s = 0.f;
  const float wih0_j = wih0[tid];
  const float bias0_j = bih0[tid] + bhh0[tid];
  const float bias1_j = bih1[tid] + bhh1[tid];
  const float wout_r = (tid < kH) ? wout[tid] : 0.f;
  const float bo = bout[0];
  float lacc = 0.f;
  __syncthreads();
  for (int t = 0; t < kT; ++t) {
    float a0 = fmaf(xs_s, wih0_j, bias0_j);
    for (int k = 0; k < kH; ++k) a0 = fmaf(whh0[tid * kH + k], h0s[k], a0);
    g4[tid] = a0;
    __syncthreads();
    if (tid < kH) {
      float ig = fsig(g4[tid]), fg = fsig(g4[tid + 256]);
      float gg = tanhf(g4[tid + 512]), og = fsig(g4[tid + 768]);
      c0r = fmaf(fg, c0r, ig * gg);
      h0s[tid] = og * tanhf(c0r);
    }
    __syncthreads();
    float a1 = bias1_j;
    for (int k = 0; k < kH; ++k) a1 = fmaf(wih1[tid * kH + k], h0s[k], a1);
    for (int k = 0; k < kH; ++k) a1 = fmaf(whh1[tid * kH + k], h1s[k], a1);
    g4[tid] = a1;
    __syncthreads();
    if (tid < kH) {
      float ig = fsig(g4[tid]), fg = fsig(g4[tid + 256]);
      float gg = tanhf(g4[tid + 512]), og = fsig(g4[tid + 768]);
      c1r = fmaf(fg, c1r, ig * gg);
      float h1 = og * tanhf(c1r);
      h1s[tid] = h1;
      g4[tid] = h1 * wout_r;
    }
    __syncthreads();
    if (tid < 64) {
      float v = g4[tid] + g4[tid + 64] + g4[tid + 128] + g4[tid + 192];
#pragma unroll
      for (int off = 32; off > 0; off >>= 1) v += __shfl_down(v, off);
      if (tid == 0) {
        float pred = v + bo;
        float d = seq[b * kT + t] - pred;
        lacc = fmaf(d, d, lacc);
        xs_s = pred;
      }
    }
    __syncthreads();
  }
  if (tid == 0) atomicAdd(loss_out, lacc * (1.0f / (float)(kB * kT)));
}

}  // namespace

extern "C" void kernel_launch(void* const* d_in, const int* in_sizes, int n_in,
                              void* d_out, int out_size, void* d_ws, size_t ws_size,
                              hipStream_t stream) {
  const float* seq = (const float*)d_in[0];
  const float* z = (const float*)d_in[1];
  const float* wih0 = (const float*)d_in[3];
  const float* whh0 = (const float*)d_in[4];
  const float* bih0 = (const float*)d_in[5];
  const float* bhh0 = (const float*)d_in[6];
  const float* wih1 = (const float*)d_in[7];
  const float* whh1 = (const float*)d_in[8];
  const float* bih1 = (const float*)d_in[9];
  const float* bhh1 = (const float*)d_in[10];
  const float* wout = (const float*)d_in[11];
  const float* bout = (const float*)d_in[12];
  float* out = (float*)d_out;

  hipMemsetAsync(out, 0, sizeof(float), stream);

  if (ws_size >= kWsNeeded) {
    H8* wpk = (H8*)d_ws;  // [3][32768] tiles: whh0, wih1, whh1
    pack_w<<<384, 256, 0, stream>>>(whh0, wih1, whh1, wpk);
    // 128KB dynamic LDS weight cache also forces 1 block/CU -> 256 blocks
    // land on 256 distinct CUs (full machine).
    const uint4* wu = (const uint4*)wpk;
    decoder_b1<<<kB, 1024, kLdsWin * 1024 * (int)sizeof(uint4), stream>>>(
        seq, z, wih0, bih0, bhh0, bih1, bhh1, wout, bout, wu,
        wu + kTiles, wu + 2 * kTiles, out);
  } else {
    decoder_fallback<<<kB, 1024, 0, stream>>>(seq, z, wih0, bih0, bhh0, whh0,
                                              wih1, whh1, bih1, bhh1, wout, bout,
                                              out);
  }
}